// Round 9
// baseline (202.384 us; speedup 1.0000x reference)
//
#include <hip/hip_runtime.h>
#include <cstdint>
#include <cstddef>

typedef unsigned short u16;
typedef u16   u16x8  __attribute__((ext_vector_type(8)));
typedef u16   u16x4  __attribute__((ext_vector_type(4)));
typedef __bf16 bf16x8 __attribute__((ext_vector_type(8)));
typedef float f32x4  __attribute__((ext_vector_type(4)));
typedef float f32x2  __attribute__((ext_vector_type(2)));

__device__ __forceinline__ float bf2f(u16 v) {
  unsigned int u = ((unsigned int)v) << 16;
  return __builtin_bit_cast(float, u);
}
__device__ __forceinline__ u16 f2bf(float f) {
  unsigned int x = __builtin_bit_cast(unsigned int, f);
  x += 0x7fffu + ((x >> 16) & 1u);   // RNE
  return (u16)(x >> 16);
}

// ---------------------------------------------------------------------------
// Kernel 1 (fat): blocks 0..255    -> transpose W21/W22 f32 -> bf16 Wt [n][k]
//                 blocks 256..1279 -> h1 = relu(x @ W1 + b1) (RAW x), 8 rows
//                                     per block; zero head rows (ws poisoned)
// ---------------------------------------------------------------------------
__global__ __launch_bounds__(256) void k_prep(const float* __restrict__ W21,
                                              const float* __restrict__ W22,
                                              u16* __restrict__ Wt,
                                              const float* __restrict__ x,
                                              const float* __restrict__ W1,
                                              const float* __restrict__ b1,
                                              u16* __restrict__ h1,
                                              float* __restrict__ head) {
  __shared__ u16 s[64][65];
  const int b = blockIdx.x;
  if (b < 256) {
    const int mat = b >> 7;
    const int tt  = b & 127;
    const int k0  = (tt >> 3) * 64;
    const int n0  = (tt & 7) * 64;
    const float* W = mat ? W22 : W21;
    const int tx = threadIdx.x & 63;
    const int ty = threadIdx.x >> 6;
#pragma unroll
    for (int i = 0; i < 16; ++i) {
      int r = i * 4 + ty;
      s[r][tx] = f2bf(W[(size_t)(k0 + r) * 512 + n0 + tx]);
    }
    __syncthreads();
    const int nbase = mat * 512 + n0;
#pragma unroll
    for (int i = 0; i < 16; ++i) {
      int r = i * 4 + ty;
      Wt[(size_t)(nbase + r) * 1024 + k0 + tx] = s[tx][r];
    }
  } else {
    const int row0 = (b - 256) * 8;
    if (threadIdx.x < 8)
      *(f32x4*)(head + 4 * (size_t)(row0 + threadIdx.x)) = f32x4{0.f, 0.f, 0.f, 0.f};
    const int c4 = threadIdx.x * 4;
    f32x4 bv = *(const f32x4*)(b1 + c4);
    f32x4 acc[8];
#pragma unroll
    for (int r = 0; r < 8; ++r) acc[r] = bv;
#pragma unroll
    for (int f = 0; f < 8; ++f) {
      f32x4 wv = *(const f32x4*)(W1 + f * 1024 + c4);
#pragma unroll
      for (int r = 0; r < 8; ++r) {
        float xv = x[(size_t)(row0 + r) * 8 + f];   // block-uniform -> s_load
#pragma unroll
        for (int e = 0; e < 4; ++e) acc[r][e] = fmaf(xv, wv[e], acc[r][e]);
      }
    }
#pragma unroll
    for (int r = 0; r < 8; ++r) {
      u16x4 o;
#pragma unroll
      for (int e = 0; e < 4; ++e) o[e] = f2bf(fmaxf(acc[r][e], 0.f));
      *(u16x4*)(h1 + (size_t)(row0 + r) * 1024 + c4) = o;
    }
  }
}

// ---------------------------------------------------------------------------
// Kernel 2: X2-GEMM, NO LDS. The mfma_16x16x32 A/B fragment (lane m=lane&15,
// k=(lane>>4)*8+j) is 16B-contiguous in row-major A / n-major Bt, and a
// wave's frag load covers 16 rows x 4 kchunks = 16 fully-used 64B segments
// -> direct global loads, register ping-pong double-buffer, ZERO barriers.
// Waves are fully independent; loads for the next K-step issue before the
// MFMAs of the current one (a full MFMA phase of latency hiding, no
// vmcnt(0)-before-barrier drain anywhere). Reuse rides L1/L2/L3.
// Epilogue: relu'd fp32 tile dotted with W31/W32 cols, 16-lane butterfly,
// atomicAdd into head[8192][4]. X2 never materialized.
// ---------------------------------------------------------------------------
__global__ __launch_bounds__(256) void k_gemm(const u16* __restrict__ A,
                                              const u16* __restrict__ Bt,
                                              const float* __restrict__ b21,
                                              const float* __restrict__ b22,
                                              const float* __restrict__ W31,
                                              const float* __restrict__ W32,
                                              float* __restrict__ head) {
  constexpr int K  = 1024;
  constexpr int BK = 32;
  constexpr int NT = K / BK;           // 32 K-steps

  const int t    = threadIdx.x;
  const int row0 = blockIdx.x * 128;   // 64 M-tiles
  const int col0 = blockIdx.y * 128;   // 8 N-tiles
  const int w    = t >> 6;
  const int lane = t & 63;
  const int wr   = w >> 1, wc = w & 1; // 2x2 wave grid, 64x64 per wave
  const int lrow = lane & 15;
  const int kq   = lane >> 4;          // k-quad: frag k = kq*8 + j

  // per-lane global fragment base pointers (advance by k)
  const u16* pa[4];
  const u16* pb[4];
#pragma unroll
  for (int i = 0; i < 4; ++i)
    pa[i] = A + (size_t)(row0 + wr * 64 + i * 16 + lrow) * K + kq * 8;
#pragma unroll
  for (int j = 0; j < 4; ++j)
    pb[j] = Bt + (size_t)(col0 + wc * 64 + j * 16 + lrow) * K + kq * 8;

  f32x4 acc[4][4];
#pragma unroll
  for (int i = 0; i < 4; ++i)
#pragma unroll
    for (int j = 0; j < 4; ++j) acc[i][j] = f32x4{0.f, 0.f, 0.f, 0.f};

  // register ping-pong: frags for steps kt (a0/b0) and kt+1 (a1/b1)
  u16x8 a0[4], b0[4], a1[4], b1[4];
#pragma unroll
  for (int i = 0; i < 4; ++i) {
    a0[i] = *(const u16x8*)(pa[i]);
    b0[i] = *(const u16x8*)(pb[i]);
    a1[i] = *(const u16x8*)(pa[i] + BK);
    b1[i] = *(const u16x8*)(pb[i] + BK);
  }

  for (int kt = 0; kt < NT; kt += 2) {
    // MFMAs for step kt consume a0/b0; reload a0/b0 with step kt+2 after
#pragma unroll
    for (int i = 0; i < 4; ++i)
#pragma unroll
      for (int j = 0; j < 4; ++j)
        acc[i][j] = __builtin_amdgcn_mfma_f32_16x16x32_bf16(
            __builtin_bit_cast(bf16x8, a0[i]),
            __builtin_bit_cast(bf16x8, b0[j]), acc[i][j], 0, 0, 0);
    if (kt + 2 < NT) {
      const int ko = (kt + 2) * BK;
#pragma unroll
      for (int i = 0; i < 4; ++i) {
        a0[i] = *(const u16x8*)(pa[i] + ko);
        b0[i] = *(const u16x8*)(pb[i] + ko);
      }
    }
#pragma unroll
    for (int i = 0; i < 4; ++i)
#pragma unroll
      for (int j = 0; j < 4; ++j)
        acc[i][j] = __builtin_amdgcn_mfma_f32_16x16x32_bf16(
            __builtin_bit_cast(bf16x8, a1[i]),
            __builtin_bit_cast(bf16x8, b1[j]), acc[i][j], 0, 0, 0);
    if (kt + 3 < NT) {
      const int ko = (kt + 3) * BK;
#pragma unroll
      for (int i = 0; i < 4; ++i) {
        a1[i] = *(const u16x8*)(pa[i] + ko);
        b1[i] = *(const u16x8*)(pb[i] + ko);
      }
    }
  }

  // ---- fused head epilogue ----
  // acc[i][j][rr]: row = row0+wr*64+i*16+kq*4+rr, col = col0+wc*64+j*16+lrow
  const bool isX21 = (col0 < 512);
  const float* Wh  = isX21 ? W31 : W32;      // [512][2] row-major
  const int   hoff = isX21 ? 0 : 2;

  float hx[16], hy[16];
#pragma unroll
  for (int n = 0; n < 16; ++n) { hx[n] = 0.f; hy[n] = 0.f; }
#pragma unroll
  for (int j = 0; j < 4; ++j) {
    int col  = col0 + wc * 64 + j * 16 + lrow;
    int wcol = col & 511;
    f32x2 wv = *(const f32x2*)(Wh + 2 * wcol);
    float bias = isX21 ? b21[col] : b22[wcol];
#pragma unroll
    for (int i = 0; i < 4; ++i)
#pragma unroll
      for (int rr = 0; rr < 4; ++rr) {
        float v = fmaxf(acc[i][j][rr] + bias, 0.f);
        hx[i * 4 + rr] = fmaf(v, wv[0], hx[i * 4 + rr]);
        hy[i * 4 + rr] = fmaf(v, wv[1], hy[i * 4 + rr]);
      }
  }
  // reduce across the 16 col-lanes (masks 1,2,4,8 stay inside the group)
#pragma unroll
  for (int m = 1; m <= 8; m <<= 1) {
#pragma unroll
    for (int n = 0; n < 16; ++n) {
      hx[n] += __shfl_xor(hx[n], m, 64);
      hy[n] += __shfl_xor(hy[n], m, 64);
    }
  }
  if (lrow == 0) {
#pragma unroll
    for (int i = 0; i < 4; ++i)
#pragma unroll
      for (int rr = 0; rr < 4; ++rr) {
        int row = row0 + wr * 64 + i * 16 + kq * 4 + rr;
        atomicAdd(head + 4 * (size_t)row + hoff,     hx[i * 4 + rr]);
        atomicAdd(head + 4 * (size_t)row + hoff + 1, hy[i * 4 + rr]);
      }
  }
}

// ---------------------------------------------------------------------------
// Kernel 3: rank-2 dual PGD QP. One thread per row; heads precomputed.
// ---------------------------------------------------------------------------
__global__ __launch_bounds__(256) void k_qp(const float* __restrict__ x,
                                            const float* __restrict__ mean_,
                                            const float* __restrict__ std_,
                                            const float* __restrict__ head,
                                            const float* __restrict__ b31,
                                            const float* __restrict__ b32,
                                            const float* __restrict__ obstacles,
                                            float* __restrict__ out) {
  const int r = blockIdx.x * 256 + threadIdx.x;
  f32x4 hd = *(const f32x4*)(head + 4 * (size_t)r);
  float p0  = hd[0] + b31[0];
  float p1v = hd[1] + b31[1];
  float pp1 = 4.f / (1.f + expf(-(hd[2] + b32[0])));
  float pp2 = 4.f / (1.f + expf(-(hd[3] + b32[1])));

  const f32x4* xp = (const f32x4*)(x + (size_t)r * 8);
  f32x4 xa = xp[0], xb = xp[1];
  float px = xa[0] * std_[0] + mean_[0];
  float py = xa[1] * std_[1] + mean_[1];
  float th = xa[2] * std_[2] + mean_[2];
  float v  = xa[3] * std_[3] + mean_[3];
  float ax = xb[0] * std_[4] + mean_[4];
  float ay = xb[1] * std_[5] + mean_[5];
  float st = sinf(th), ct = cosf(th);
  float Lf2b = 2.f * v * v;

  float G0[9], G1[9], q[9];
  float s00 = 0.f, s01 = 0.f, s11 = 0.f;
#pragma unroll
  for (int m = 0; m < 9; ++m) {
    float ox, oy, orad;
    if (m < 8) {
      ox = obstacles[m * 3]; oy = obstacles[m * 3 + 1]; orad = obstacles[m * 3 + 2];
    } else { ox = ax; oy = ay; orad = 0.5f; }
    float R  = 0.6f + orad;                  // AGENT_RADIUS + orad + SAFETY
    float dx = px - ox, dy = py - oy;
    float bar  = dx * dx + dy * dy - R * R;
    float dct  = dx * ct + dy * st;
    float bdot = 2.f * v * dct;
    float g0 = 2.f * v * (dx * st - dy * ct);   // -LgLfbu1
    float g1 = -2.f * dct;                      // -LgLfbu2
    float h  = Lf2b + (pp1 + pp2) * bdot + pp1 * pp2 * bar;
    G0[m] = g0; G1[m] = g1;
    q[m] = g0 * p0 + g1 * p1v + h;
    s00 += g0 * g0; s01 += g0 * g1; s11 += g1 * g1;
  }
  float L = sqrtf(s00 * s00 + 2.f * s01 * s01 + s11 * s11) + 1e-6f;
  float alpha = 1.f / L;

  float lam[9];
#pragma unroll
  for (int m = 0; m < 9; ++m) lam[m] = 0.f;
  for (int it = 0; it < 300; ++it) {
    float pr0[9], pr1[9];
#pragma unroll
    for (int m = 0; m < 9; ++m) { pr0[m] = G0[m] * lam[m]; pr1[m] = G1[m] * lam[m]; }
    float t0 = (((pr0[0] + pr0[1]) + (pr0[2] + pr0[3])) +
                ((pr0[4] + pr0[5]) + (pr0[6] + pr0[7]))) + pr0[8];
    float t1 = (((pr1[0] + pr1[1]) + (pr1[2] + pr1[3])) +
                ((pr1[4] + pr1[5]) + (pr1[6] + pr1[7]))) + pr1[8];
#pragma unroll
    for (int m = 0; m < 9; ++m) {
      float g = fmaf(G0[m], t0, fmaf(G1[m], t1, q[m]));
      lam[m] = fmaxf(fmaf(-alpha, g, lam[m]), 0.f);
    }
  }
  float u0 = -p0, u1 = -p1v;
#pragma unroll
  for (int m = 0; m < 9; ++m) { u0 = fmaf(-G0[m], lam[m], u0); u1 = fmaf(-G1[m], lam[m], u1); }
  *(f32x2*)(out + 2 * (size_t)r) = f32x2{u0, u1};
}

// ---------------------------------------------------------------------------
extern "C" void kernel_launch(void* const* d_in, const int* in_sizes, int n_in,
                              void* d_out, int out_size, void* d_ws, size_t ws_size,
                              hipStream_t stream) {
  const float* x    = (const float*)d_in[0];
  const float* mean_= (const float*)d_in[1];
  const float* std_ = (const float*)d_in[2];
  const float* W1   = (const float*)d_in[3];
  const float* b1   = (const float*)d_in[4];
  const float* W21  = (const float*)d_in[5];
  const float* b21  = (const float*)d_in[6];
  const float* W22  = (const float*)d_in[7];
  const float* b22  = (const float*)d_in[8];
  // d_in[9],[10] = W23,b23 : dead code in reference (x33 unused)
  const float* W31  = (const float*)d_in[11];
  const float* b31  = (const float*)d_in[12];
  const float* W32  = (const float*)d_in[13];
  const float* b32  = (const float*)d_in[14];
  // d_in[15],[16] = W33,b33 : dead code
  const float* obst = (const float*)d_in[17];
  float* out = (float*)d_out;

  char* ws = (char*)d_ws;
  u16*   Wt   = (u16*)ws;                                   // 2 MB
  u16*   h1   = (u16*)(ws + (size_t)(1 << 21));             // 16 MB
  float* head = (float*)(ws + (size_t)(1 << 21) + (size_t)(1 << 24)); // 128 KB

  k_prep<<<256 + 1024, 256, 0, stream>>>(W21, W22, Wt, x, W1, b1, h1, head);
  k_gemm<<<dim3(64, 8), 256, 0, stream>>>(h1, Wt, b21, b22, W31, W32, head);
  k_qp  <<<32, 256, 0, stream>>>(x, mean_, std_, head, b31, b32, obst, out);
}

// Round 10
// 164.065 us; speedup vs baseline: 1.2336x; 1.2336x over previous
//
#include <hip/hip_runtime.h>
#include <cstdint>
#include <cstddef>

typedef unsigned short u16;
typedef u16   u16x8  __attribute__((ext_vector_type(8)));
typedef u16   u16x4  __attribute__((ext_vector_type(4)));
typedef __bf16 bf16x8 __attribute__((ext_vector_type(8)));
typedef float f32x4  __attribute__((ext_vector_type(4)));
typedef float f32x2  __attribute__((ext_vector_type(2)));

__device__ __forceinline__ float bf2f(u16 v) {
  unsigned int u = ((unsigned int)v) << 16;
  return __builtin_bit_cast(float, u);
}
__device__ __forceinline__ u16 f2bf(float f) {
  unsigned int x = __builtin_bit_cast(unsigned int, f);
  x += 0x7fffu + ((x >> 16) & 1u);   // RNE
  return (u16)(x >> 16);
}

// async global->LDS, 16B per lane. LDS dest must be wave-uniform base + lane*16.
__device__ __forceinline__ void gld_lds16(const u16* g, u16* l) {
  __builtin_amdgcn_global_load_lds(
      (const __attribute__((address_space(1))) unsigned int*)g,
      (__attribute__((address_space(3))) unsigned int*)l, 16, 0, 0);
}

// ---------------------------------------------------------------------------
// Kernel 1 (fat): blocks 0..255    -> transpose W21/W22 f32 -> bf16 Wt [n][k]
//                 blocks 256..1279 -> h1 = relu(x @ W1 + b1) (RAW x), 8 rows
//                                     per block; zero head rows (ws poisoned)
// ---------------------------------------------------------------------------
__global__ __launch_bounds__(256) void k_prep(const float* __restrict__ W21,
                                              const float* __restrict__ W22,
                                              u16* __restrict__ Wt,
                                              const float* __restrict__ x,
                                              const float* __restrict__ W1,
                                              const float* __restrict__ b1,
                                              u16* __restrict__ h1,
                                              float* __restrict__ head) {
  __shared__ u16 s[64][65];
  const int b = blockIdx.x;
  if (b < 256) {
    const int mat = b >> 7;
    const int tt  = b & 127;
    const int k0  = (tt >> 3) * 64;
    const int n0  = (tt & 7) * 64;
    const float* W = mat ? W22 : W21;
    const int tx = threadIdx.x & 63;
    const int ty = threadIdx.x >> 6;
#pragma unroll
    for (int i = 0; i < 16; ++i) {
      int r = i * 4 + ty;
      s[r][tx] = f2bf(W[(size_t)(k0 + r) * 512 + n0 + tx]);
    }
    __syncthreads();
    const int nbase = mat * 512 + n0;
#pragma unroll
    for (int i = 0; i < 16; ++i) {
      int r = i * 4 + ty;
      Wt[(size_t)(nbase + r) * 1024 + k0 + tx] = s[tx][r];
    }
  } else {
    const int row0 = (b - 256) * 8;
    if (threadIdx.x < 8)
      *(f32x4*)(head + 4 * (size_t)(row0 + threadIdx.x)) = f32x4{0.f, 0.f, 0.f, 0.f};
    const int c4 = threadIdx.x * 4;
    f32x4 bv = *(const f32x4*)(b1 + c4);
    f32x4 acc[8];
#pragma unroll
    for (int r = 0; r < 8; ++r) acc[r] = bv;
#pragma unroll
    for (int f = 0; f < 8; ++f) {
      f32x4 wv = *(const f32x4*)(W1 + f * 1024 + c4);
#pragma unroll
      for (int r = 0; r < 8; ++r) {
        float xv = x[(size_t)(row0 + r) * 8 + f];   // block-uniform -> s_load
#pragma unroll
        for (int e = 0; e < 4; ++e) acc[r][e] = fmaf(xv, wv[e], acc[r][e]);
      }
    }
#pragma unroll
    for (int r = 0; r < 8; ++r) {
      u16x4 o;
#pragma unroll
      for (int e = 0; e < 4; ++e) o[e] = f2bf(fmaxf(acc[r][e], 0.f));
      *(u16x4*)(h1 + (size_t)(row0 + r) * 1024 + c4) = o;
    }
  }
}

// ---------------------------------------------------------------------------
// Kernel 2: X2-GEMM (mfma 16x16x32, 128x128 tile, BK=64) + fused head epilogue.
// Staging: global_load_lds DMA, double-buffered LDS (2x16KB A + 2x16KB B =
// 64 KB), ONE barrier per K-iteration; BK=64 -> only 16 barrier/drain events,
// and each DMA has a full doubled compute phase (~2x BK=32) to complete
// before the vmcnt(0)-before-barrier drain.
// Swizzle: stored chunk c (16B) of row r holds global kchunk c ^ (r&7).
//  - read side: b128 conflicts count per 16-lane quarter-wave; lrow 0..15 hit
//    each of the 8 bank-groups exactly 2x -> free [R8: measured 0 conflicts].
//  - DMA dest is wave-uniform + lane*16 (structural), global fetch still
//    covers whole 128B row segments -> coalescing intact.
// X2 never materialized: relu'd fp32 tile dotted with W31/W32 cols,
// col-lane butterfly reduce, atomicAdd into head[8192][4].
// ---------------------------------------------------------------------------
__global__ __launch_bounds__(256) void k_gemm(const u16* __restrict__ A,
                                              const u16* __restrict__ Bt,
                                              const float* __restrict__ b21,
                                              const float* __restrict__ b22,
                                              const float* __restrict__ W31,
                                              const float* __restrict__ W32,
                                              float* __restrict__ head) {
  constexpr int K  = 1024;
  constexpr int BK = 64;
  constexpr int NT = K / BK;           // 16 K-tiles
  __shared__ u16 As[2][128 * 64];      // 16 KB each
  __shared__ u16 Bs[2][128 * 64];      // total 64 KB (static limit; 2 blk/CU)

  const int t    = threadIdx.x;
  const int row0 = blockIdx.x * 128;   // 64 M-tiles
  const int col0 = blockIdx.y * 128;   // 8 N-tiles
  const int w    = t >> 6;
  const int lane = t & 63;
  const int wr   = w >> 1, wc = w & 1; // 2x2 wave grid, 64x64 per wave
  const int lrow = lane & 15;
  const int kq   = lane >> 4;          // frag k-chunk within a k32 step

  // staging slots m=0..3: s = t + 256m; row = s>>3, stored chunk = s&7,
  // fetched global kchunk = (s&7) ^ ((s>>3)&7)
  const u16* gA[4];
  const u16* gB[4];
  int lo[4];
#pragma unroll
  for (int m = 0; m < 4; ++m) {
    const int s  = t + 256 * m;
    const int gc = (s & 7) ^ ((s >> 3) & 7);
    gA[m] = A  + (size_t)(row0 + (s >> 3)) * K + gc * 8;
    gB[m] = Bt + (size_t)(col0 + (s >> 3)) * K + gc * 8;
    lo[m] = s * 8;
  }
  // read-side physical chunk offsets for k32-steps 0/1 (logical chunk
  // s32*4+kq at row r -> stored chunk (s32*4+kq)^(r&7); r&7 == lrow&7)
  const int po0 = (((0 * 4) + kq) ^ (lrow & 7)) * 8;
  const int po1 = (((1 * 4) + kq) ^ (lrow & 7)) * 8;

  f32x4 acc[4][4];
#pragma unroll
  for (int i = 0; i < 4; ++i)
#pragma unroll
    for (int j = 0; j < 4; ++j) acc[i][j] = f32x4{0.f, 0.f, 0.f, 0.f};

  // prologue: DMA tile 0 into buffer 0
#pragma unroll
  for (int m = 0; m < 4; ++m) {
    gld_lds16(gA[m], As[0] + lo[m]);
    gld_lds16(gB[m], Bs[0] + lo[m]);
  }

  for (int kt = 0; kt < NT; ++kt) {
    const int cur = kt & 1, nxt = cur ^ 1;
    __syncthreads();                   // drains DMA into buf[cur]; orders WAR

    if (kt + 1 < NT) {                 // DMA next tile into buf[nxt]
      const int ko = (kt + 1) * BK;
#pragma unroll
      for (int m = 0; m < 4; ++m) {
        gld_lds16(gA[m] + ko, As[nxt] + lo[m]);
        gld_lds16(gB[m] + ko, Bs[nxt] + lo[m]);
      }
    }

#pragma unroll
    for (int s32 = 0; s32 < 2; ++s32) {
      const int po = s32 ? po1 : po0;
      bf16x8 af[4], bfr[4];
#pragma unroll
      for (int i = 0; i < 4; ++i)
        af[i] = __builtin_bit_cast(bf16x8,
            *(const u16x8*)(As[cur] + (wr * 64 + i * 16 + lrow) * 64 + po));
#pragma unroll
      for (int j = 0; j < 4; ++j)
        bfr[j] = __builtin_bit_cast(bf16x8,
            *(const u16x8*)(Bs[cur] + (wc * 64 + j * 16 + lrow) * 64 + po));
#pragma unroll
      for (int i = 0; i < 4; ++i)
#pragma unroll
        for (int j = 0; j < 4; ++j)
          acc[i][j] = __builtin_amdgcn_mfma_f32_16x16x32_bf16(af[i], bfr[j], acc[i][j], 0, 0, 0);
    }
  }

  // ---- fused head epilogue ----
  // acc[i][j][rr]: row = row0+wr*64+i*16+kq*4+rr, col = col0+wc*64+j*16+lrow
  const bool isX21 = (col0 < 512);
  const float* Wh  = isX21 ? W31 : W32;      // [512][2] row-major
  const int   hoff = isX21 ? 0 : 2;

  float hx[16], hy[16];
#pragma unroll
  for (int n = 0; n < 16; ++n) { hx[n] = 0.f; hy[n] = 0.f; }
#pragma unroll
  for (int j = 0; j < 4; ++j) {
    int col  = col0 + wc * 64 + j * 16 + lrow;
    int wcol = col & 511;
    f32x2 wv = *(const f32x2*)(Wh + 2 * wcol);
    float bias = isX21 ? b21[col] : b22[wcol];
#pragma unroll
    for (int i = 0; i < 4; ++i)
#pragma unroll
      for (int rr = 0; rr < 4; ++rr) {
        float v = fmaxf(acc[i][j][rr] + bias, 0.f);
        hx[i * 4 + rr] = fmaf(v, wv[0], hx[i * 4 + rr]);
        hy[i * 4 + rr] = fmaf(v, wv[1], hy[i * 4 + rr]);
      }
  }
  // reduce across the 16 col-lanes (masks 1,2,4,8 stay inside the group)
#pragma unroll
  for (int m = 1; m <= 8; m <<= 1) {
#pragma unroll
    for (int n = 0; n < 16; ++n) {
      hx[n] += __shfl_xor(hx[n], m, 64);
      hy[n] += __shfl_xor(hy[n], m, 64);
    }
  }
  if (lrow == 0) {
#pragma unroll
    for (int i = 0; i < 4; ++i)
#pragma unroll
      for (int rr = 0; rr < 4; ++rr) {
        int row = row0 + wr * 64 + i * 16 + kq * 4 + rr;
        atomicAdd(head + 4 * (size_t)row + hoff,     hx[i * 4 + rr]);
        atomicAdd(head + 4 * (size_t)row + hoff + 1, hy[i * 4 + rr]);
      }
  }
}

// ---------------------------------------------------------------------------
// Kernel 3: rank-2 dual PGD QP. One thread per row; heads precomputed.
// ---------------------------------------------------------------------------
__global__ __launch_bounds__(256) void k_qp(const float* __restrict__ x,
                                            const float* __restrict__ mean_,
                                            const float* __restrict__ std_,
                                            const float* __restrict__ head,
                                            const float* __restrict__ b31,
                                            const float* __restrict__ b32,
                                            const float* __restrict__ obstacles,
                                            float* __restrict__ out) {
  const int r = blockIdx.x * 256 + threadIdx.x;
  f32x4 hd = *(const f32x4*)(head + 4 * (size_t)r);
  float p0  = hd[0] + b31[0];
  float p1v = hd[1] + b31[1];
  float pp1 = 4.f / (1.f + expf(-(hd[2] + b32[0])));
  float pp2 = 4.f / (1.f + expf(-(hd[3] + b32[1])));

  const f32x4* xp = (const f32x4*)(x + (size_t)r * 8);
  f32x4 xa = xp[0], xb = xp[1];
  float px = xa[0] * std_[0] + mean_[0];
  float py = xa[1] * std_[1] + mean_[1];
  float th = xa[2] * std_[2] + mean_[2];
  float v  = xa[3] * std_[3] + mean_[3];
  float ax = xb[0] * std_[4] + mean_[4];
  float ay = xb[1] * std_[5] + mean_[5];
  float st = sinf(th), ct = cosf(th);
  float Lf2b = 2.f * v * v;

  float G0[9], G1[9], q[9];
  float s00 = 0.f, s01 = 0.f, s11 = 0.f;
#pragma unroll
  for (int m = 0; m < 9; ++m) {
    float ox, oy, orad;
    if (m < 8) {
      ox = obstacles[m * 3]; oy = obstacles[m * 3 + 1]; orad = obstacles[m * 3 + 2];
    } else { ox = ax; oy = ay; orad = 0.5f; }
    float R  = 0.6f + orad;                  // AGENT_RADIUS + orad + SAFETY
    float dx = px - ox, dy = py - oy;
    float bar  = dx * dx + dy * dy - R * R;
    float dct  = dx * ct + dy * st;
    float bdot = 2.f * v * dct;
    float g0 = 2.f * v * (dx * st - dy * ct);   // -LgLfbu1
    float g1 = -2.f * dct;                      // -LgLfbu2
    float h  = Lf2b + (pp1 + pp2) * bdot + pp1 * pp2 * bar;
    G0[m] = g0; G1[m] = g1;
    q[m] = g0 * p0 + g1 * p1v + h;
    s00 += g0 * g0; s01 += g0 * g1; s11 += g1 * g1;
  }
  float L = sqrtf(s00 * s00 + 2.f * s01 * s01 + s11 * s11) + 1e-6f;
  float alpha = 1.f / L;

  float lam[9];
#pragma unroll
  for (int m = 0; m < 9; ++m) lam[m] = 0.f;
  for (int it = 0; it < 300; ++it) {
    float pr0[9], pr1[9];
#pragma unroll
    for (int m = 0; m < 9; ++m) { pr0[m] = G0[m] * lam[m]; pr1[m] = G1[m] * lam[m]; }
    float t0 = (((pr0[0] + pr0[1]) + (pr0[2] + pr0[3])) +
                ((pr0[4] + pr0[5]) + (pr0[6] + pr0[7]))) + pr0[8];
    float t1 = (((pr1[0] + pr1[1]) + (pr1[2] + pr1[3])) +
                ((pr1[4] + pr1[5]) + (pr1[6] + pr1[7]))) + pr1[8];
#pragma unroll
    for (int m = 0; m < 9; ++m) {
      float g = fmaf(G0[m], t0, fmaf(G1[m], t1, q[m]));
      lam[m] = fmaxf(fmaf(-alpha, g, lam[m]), 0.f);
    }
  }
  float u0 = -p0, u1 = -p1v;
#pragma unroll
  for (int m = 0; m < 9; ++m) { u0 = fmaf(-G0[m], lam[m], u0); u1 = fmaf(-G1[m], lam[m], u1); }
  *(f32x2*)(out + 2 * (size_t)r) = f32x2{u0, u1};
}

// ---------------------------------------------------------------------------
extern "C" void kernel_launch(void* const* d_in, const int* in_sizes, int n_in,
                              void* d_out, int out_size, void* d_ws, size_t ws_size,
                              hipStream_t stream) {
  const float* x    = (const float*)d_in[0];
  const float* mean_= (const float*)d_in[1];
  const float* std_ = (const float*)d_in[2];
  const float* W1   = (const float*)d_in[3];
  const float* b1   = (const float*)d_in[4];
  const float* W21  = (const float*)d_in[5];
  const float* b21  = (const float*)d_in[6];
  const float* W22  = (const float*)d_in[7];
  const float* b22  = (const float*)d_in[8];
  // d_in[9],[10] = W23,b23 : dead code in reference (x33 unused)
  const float* W31  = (const float*)d_in[11];
  const float* b31  = (const float*)d_in[12];
  const float* W32  = (const float*)d_in[13];
  const float* b32  = (const float*)d_in[14];
  // d_in[15],[16] = W33,b33 : dead code
  const float* obst = (const float*)d_in[17];
  float* out = (float*)d_out;

  char* ws = (char*)d_ws;
  u16*   Wt   = (u16*)ws;                                   // 2 MB
  u16*   h1   = (u16*)(ws + (size_t)(1 << 21));             // 16 MB
  float* head = (float*)(ws + (size_t)(1 << 21) + (size_t)(1 << 24)); // 128 KB

  k_prep<<<256 + 1024, 256, 0, stream>>>(W21, W22, Wt, x, W1, b1, h1, head);
  k_gemm<<<dim3(64, 8), 256, 0, stream>>>(h1, Wt, b21, b22, W31, W32, head);
  k_qp  <<<32, 256, 0, stream>>>(x, mean_, std_, head, b31, b32, obst, out);
}